// Round 10
// baseline (95.663 us; speedup 1.0000x reference)
//
#include <hip/hip_runtime.h>

// CRF-RNN (C=2) on 56x56, 10 iterations in ONE kernel, plain launch.
// 196 blocks x 256 thr -> exactly <=1 block per CU (uniform, no CU-sharing
// skew at the grid syncs); all blocks trivially co-resident.
//
// Math: s = sigmoid(q1-q0); d = (2u-1) - alpha - beta*t_sp/n_sp - gamma*t_bl/n_bl.
//  * spatial kernel separable: 56-tap row conv + column fold; n_sp = Sx*Sy.
//  * bilateral: theta_beta=3 -> exp(-dg^2/6) < 3e-19 for |dg|>16 of 255.
//    Pixels counting-sorted by intensity ONCE (deterministic, stable,
//    atomic-free); per j only the +-16-bucket band is visited (~390 pairs).
//  * norms s-independent: iter-0 computes them, reciprocals in registers.
//
// Sync: zero-sentinel flow control (proven r8/r9). Sigmoid outputs are never
// 0.0f; 9 distinct pre-zeroed publish buffers; publish = 16 relaxed agent
// stores (LLC-coherent, no L2 maintenance); consume = re-read the field with
// global_load_dwordx4 sc0 sc1 until nonzero. NEW: incremental re-poll -- after
// the first full read, only quads still containing 0.0 are re-loaded
// (per-lane miss mask, exec-masked loads) -> ~10x less poll traffic.

namespace {

constexpr int NPIX = 3136;
constexpr int WIMG = 56;
constexpr int JPB  = 16;              // j-pixels per block
constexpr int LPJ  = 16;              // lanes per j
constexpr int NBLK = NPIX / JPB;      // 196 blocks (1 per CU)
constexpr int NTHR = 256;             // 4 waves
constexpr int NBUF = 9;
constexpr int BAND = 16;              // intensity band (buckets)

constexpr float LOG2E = 1.4426950408889634f;
constexpr float C1 = -LOG2E / 18.0f;
constexpr float C2 = -LOG2E / 51200.0f;
constexpr float C3 = -LOG2E / 6.0f;

// LDS pool layout (bytes, 16-aligned)
constexpr int O_SSH  = 0;         // float[3136]  s, linear
constexpr int O_SSRT = 12544;     // float[3136]  s, sorted (init: g tmp)
constexpr int O_XYV  = 25088;     // float[3136]  x+64y, sorted (init: H lo)
constexpr int O_GSRT = 37632;     // float[3136]  g, sorted      (init: H hi)
constexpr int O_RANK = 50176;     // u16[3136]
constexpr int O_OFF  = 56448;     // u32[257] (pad to 1040)
constexpr int O_W1C  = 57488;     // float[4][128]
constexpr int O_WSY  = 59536;     // float[16][56]  per-j column weights
constexpr int O_ROWC = 63120;     // float[56][17]  row conv (pad stride 17)
constexpr int O_XLOC = 66928;     // int[16]
constexpr int O_SOUT = 66992;     // float[16]
constexpr int POOLSZ = 67056;

#define REDUCE16(v) \
    { v += __shfl_xor(v, 1); v += __shfl_xor(v, 2); \
      v += __shfl_xor(v, 4); v += __shfl_xor(v, 8); }

__global__ __launch_bounds__(NTHR) void crf_all(
    const float* __restrict__ inp,
    const float* __restrict__ spw, const float* __restrict__ blw,
    const float* __restrict__ cmw,
    float* sbufs, float* __restrict__ out)
{
    __shared__ __align__(16) unsigned char pool[POOLSZ];
    float*  s_sh    = (float*)(pool + O_SSH);
    float4* s_sh4   = (float4*)(pool + O_SSH);
    float*  s_srt   = (float*)(pool + O_SSRT);
    float*  xyv_srt = (float*)(pool + O_XYV);
    float*  g_srt   = (float*)(pool + O_GSRT);
    unsigned short* rank = (unsigned short*)(pool + O_RANK);
    unsigned*       offs = (unsigned*)(pool + O_OFF);
    float*  W1c   = (float*)(pool + O_W1C);
    float*  wsy   = (float*)(pool + O_WSY);
    float*  rowc  = (float*)(pool + O_ROWC);
    int*    xloc  = (int*)(pool + O_XLOC);
    float*  s_out = (float*)(pool + O_SOUT);
    unsigned short* H  = (unsigned short*)(pool + O_XYV);  // init union
    unsigned*       Hz = (unsigned*)(pool + O_XYV);
    float*  tmpg = s_srt;                                   // init alias

    const int t   = threadIdx.x;
    const int bid = blockIdx.x;
    const int sub = t & (LPJ - 1);
    const int jl  = t >> 4;
    const int j   = bid * JPB + jl;
    const int xj  = j % WIMG;
    const int yj  = j / WIMG;
    const float xjf = (float)xj, yjf = (float)yj;

    const float uj = inp[j];
    const float gj = inp[NPIX + j] * 255.0f;

    const float e0 = cmw[2] - cmw[0];
    const float e1 = cmw[3] - cmw[1];
    const float alpha = e0 * (spw[0] + blw[0]) + e1 * (spw[2] + blw[2]);
    const float beta  = e0 * (spw[1] - spw[0]) + e1 * (spw[3] - spw[2]);
    const float gamma = e0 * (blw[1] - blw[0]) + e1 * (blw[3] - blw[2]);

    // ---- I0: stage u,g; W1 table; per-j wsy rows; xloc; zero H
    {
        const float4* u4 = (const float4*)inp;
        const float4* g4 = (const float4*)(inp + NPIX);
        float4* tg4 = (float4*)tmpg;
        for (int m = t; m < NPIX / 4; m += NTHR) {
            s_sh4[m] = u4[m];
            float4 g = g4[m];
            g.x *= 255.f; g.y *= 255.f; g.z *= 255.f; g.w *= 255.f;
            tg4[m] = g;
        }
        for (int i = t; i < 512; i += NTHR) {       // W1c[r][i]=exp2(C1(56+r-i)^2)
            int r = i >> 7, ii = i & 127;
            float dd = (float)(56 + r - ii);
            W1c[i] = __builtin_amdgcn_exp2f(C1 * dd * dd);
        }
        for (int idx = t; idx < JPB * 56; idx += NTHR) {  // wsy[jlw][y]
            int jlw = idx / 56, y = idx - jlw * 56;
            int yjw = (bid * JPB + jlw) / WIMG;
            float dd = (float)(yjw - y);
            wsy[idx] = __builtin_amdgcn_exp2f(C1 * dd * dd);
        }
        if (t < JPB) xloc[t] = (bid * JPB + t) % WIMG;
        for (int i = t; i < 6272; i += NTHR) Hz[i] = 0u;
    }
    __syncthreads();
    // ---- I1: per-chunk histogram (49 chunks x 64 px, single-owner rows)
    if (t < 49) {
        unsigned short* Hr = H + t * 256;
        const int mb = t * 64;
        for (int i = 0; i < 64; ++i) {
            int b = (int)tmpg[mb + i]; b = b > 255 ? 255 : b;
            Hr[b] = (unsigned short)(Hr[b] + 1);
        }
    }
    __syncthreads();
    // ---- I2: column prefix per bucket; totals -> offs[b]
    {
        unsigned run = 0;
        for (int c = 0; c < 49; ++c) {
            unsigned short v = H[c * 256 + t];
            H[c * 256 + t] = (unsigned short)run;
            run += v;
        }
        offs[t] = run;
    }
    __syncthreads();
    // ---- I3: exclusive scan offs[0..255]
    if (t < 64) {
        unsigned v0 = offs[4 * t], v1 = offs[4 * t + 1];
        unsigned v2 = offs[4 * t + 2], v3 = offs[4 * t + 3];
        unsigned sum = v0 + v1 + v2 + v3;
        unsigned sc = sum;
        for (int d = 1; d < 64; d <<= 1) {
            unsigned n = __shfl_up(sc, d);
            if (t >= d) sc += n;
        }
        unsigned base = sc - sum;
        offs[4 * t] = base;
        offs[4 * t + 1] = base + v0;
        offs[4 * t + 2] = base + v0 + v1;
        offs[4 * t + 3] = base + v0 + v1 + v2;
        if (t == 63) offs[256] = sc;
    }
    __syncthreads();
    // ---- I4: stable deterministic ranks
    if (t < 49) {
        unsigned short* Hr = H + t * 256;
        const int mb = t * 64;
        for (int i = 0; i < 64; ++i) {
            int b = (int)tmpg[mb + i]; b = b > 255 ? 255 : b;
            rank[mb + i] = (unsigned short)(offs[b] + Hr[b]);
            Hr[b] = (unsigned short)(Hr[b] + 1);
        }
    }
    __syncthreads();
    // ---- I5: sorted pos/intensity (overwrites H region)
    for (int m = t; m < NPIX; m += NTHR) {
        int r = rank[m];
        int y = m / WIMG;
        int x = m - y * WIMG;
        xyv_srt[r] = (float)(x + 64 * y);
        g_srt[r] = tmpg[m];
    }
    __syncthreads();
    // ---- I6: s_srt for iteration 0
    for (int m = t; m < NPIX; m += NTHR) s_srt[rank[m]] = s_sh[m];
    __syncthreads();

    // n_sp = Sx*Sy (separable, exact)
    float sx = 0.f, sy = 0.f;
    for (int xi = sub; xi < 56; xi += LPJ) {
        float dd = xjf - (float)xi;
        sx += __builtin_amdgcn_exp2f(C1 * dd * dd);
    }
    REDUCE16(sx);
    for (int yi = sub; yi < 56; yi += LPJ) {
        float dd = yjf - (float)yi;
        sy += __builtin_amdgcn_exp2f(C1 * dd * dd);
    }
    REDUCE16(sy);
    const float rnsp = 1.0f / (sx * sy);

    int bj = (int)gj; bj = bj > 255 ? 255 : bj;
    const int blo = (int)offs[bj < BAND ? 0 : bj - BAND];
    const int bhi = (int)offs[(bj + BAND > 255 ? 255 : bj + BAND) + 1];

    // separable spatial: row conv (56x16 outputs over 256 thr) + column fold
    auto spatial = [&]() -> float {
        for (int idx = t; idx < 56 * JPB; idx += NTHR) {
            const int y = idx >> 4, c = idx & 15;
            const int X = xloc[c];
            const int r = X & 3;
            const float4* R = (const float4*)(W1c + r * 128 + (56 + r - X));
            const float4* S = s_sh4 + y * 14;
            float acc = 0.f;
#pragma unroll
            for (int q = 0; q < 14; ++q) {
                float4 w = R[q], sv = S[q];
                acc = fmaf(w.x, sv.x, acc); acc = fmaf(w.y, sv.y, acc);
                acc = fmaf(w.z, sv.z, acc); acc = fmaf(w.w, sv.w, acc);
            }
            rowc[y * 17 + c] = acc;
        }
        __syncthreads();
        const float* wsy_j = wsy + jl * 56;
        float part = 0.f;
        for (int y = sub; y < 56; y += LPJ)
            part = fmaf(wsy_j[y], rowc[y * 17 + jl], part);
        REDUCE16(part);
        return part;
    };

    // publish + zero-sentinel sync (incremental re-poll) + restage
    auto publish_sync = [&](float s, float* buf) {
        if (sub == 0) s_out[jl] = s;
        __syncthreads();
        if (t < 64) {
            if (t < JPB)
                __hip_atomic_store(&buf[bid * JPB + t], s_out[t],
                                   __ATOMIC_RELAXED, __HIP_MEMORY_SCOPE_AGENT);
            const float4* src = (const float4*)buf;
            float4 vv[12]; float4 vt;
            unsigned miss = (t < 16) ? 0x1FFFu : 0x0FFFu;
            for (;;) {
#pragma unroll
                for (int q = 0; q < 12; ++q)
                    if (miss & (1u << q))
                        asm volatile("global_load_dwordx4 %0, %1, off sc0 sc1"
                                     : "=&v"(vv[q]) : "v"(src + q * 64 + t));
                if (miss & 0x1000u)
                    asm volatile("global_load_dwordx4 %0, %1, off sc0 sc1"
                                 : "=&v"(vt) : "v"(src + 768 + t));
                asm volatile("s_waitcnt vmcnt(0)" ::: "memory");
#pragma unroll
                for (int q = 0; q < 12; ++q)
                    if (miss & (1u << q)) {
                        float mn = fminf(fminf(vv[q].x, vv[q].y),
                                         fminf(vv[q].z, vv[q].w));
                        if (mn != 0.0f) miss &= ~(1u << q);
                    }
                if (miss & 0x1000u) {
                    float mn = fminf(fminf(vt.x, vt.y), fminf(vt.z, vt.w));
                    if (mn != 0.0f) miss &= ~0x1000u;
                }
                if (!__any(miss != 0u)) break;
                __builtin_amdgcn_s_sleep(1);
            }
#pragma unroll
            for (int q = 0; q < 12; ++q) s_sh4[q * 64 + t] = vv[q];
            if (t < 16) s_sh4[768 + t] = vt;
        }
        __syncthreads();
        for (int m = t; m < NPIX; m += NTHR) s_srt[rank[m]] = s_sh[m];
        __syncthreads();
    };

    const float base = 2.0f * uj - 1.0f - alpha;
    float rnbl, s;

    // ---- iteration 0 (s = u), also accumulates n_bl over the band
    {
        float tsp = spatial();
        float acc = 0.f, nacc = 0.f;
        for (int p = blo + sub; p < bhi; p += LPJ) {
            float xyv = xyv_srt[p], gv = g_srt[p], sv = s_srt[p];
            float yi = floorf(xyv * 0.015625f);
            float xi = fmaf(-64.f, yi, xyv);
            float ux = xi - xjf, vy = yi - yjf;
            float r2 = fmaf(ux, ux, vy * vy);
            float dg = gv - gj;
            float w = __builtin_amdgcn_exp2f(fmaf(dg * C3, dg, r2 * C2));
            acc = fmaf(w, sv, acc);
            nacc += w;
        }
        REDUCE16(acc); REDUCE16(nacc);
        rnbl = 1.0f / nacc;
        float d = base - beta * (tsp * rnsp) - gamma * (acc * rnbl);
        s = 1.0f / (1.0f + __builtin_amdgcn_exp2f(-d * LOG2E));
    }
    publish_sync(s, sbufs);

    // ---- iterations 1..9
    for (int k = 1; k < 10; ++k) {
        float tsp = spatial();
        float acc = 0.f;
        for (int p = blo + sub; p < bhi; p += LPJ) {
            float xyv = xyv_srt[p], gv = g_srt[p], sv = s_srt[p];
            float yi = floorf(xyv * 0.015625f);
            float xi = fmaf(-64.f, yi, xyv);
            float ux = xi - xjf, vy = yi - yjf;
            float r2 = fmaf(ux, ux, vy * vy);
            float dg = gv - gj;
            float w = __builtin_amdgcn_exp2f(fmaf(dg * C3, dg, r2 * C2));
            acc = fmaf(w, sv, acc);
        }
        REDUCE16(acc);
        float d = base - beta * (tsp * rnsp) - gamma * (acc * rnbl);
        s = 1.0f / (1.0f + __builtin_amdgcn_exp2f(-d * LOG2E));
        if (k < 9) publish_sync(s, sbufs + k * NPIX);
        else if (sub == 0) out[j] = s;   // softmax(q)[1] = sigmoid(d)
    }
}

}  // namespace

extern "C" void kernel_launch(void* const* d_in, const int* in_sizes, int n_in,
                              void* d_out, int out_size, void* d_ws, size_t ws_size,
                              hipStream_t stream) {
    const float* inp = (const float*)d_in[0];
    const float* spw = (const float*)d_in[1];
    const float* blw = (const float*)d_in[2];
    const float* cmw = (const float*)d_in[3];
    float* sbufs = (float*)d_ws;          // 9 x 3136 floats, zero = "not yet"
    float* out = (float*)d_out;

    hipMemsetAsync(sbufs, 0, NBUF * NPIX * sizeof(float), stream);
    crf_all<<<dim3(NBLK), dim3(NTHR), 0, stream>>>(inp, spw, blw, cmw,
                                                   sbufs, out);
}

// Round 11
// 91.022 us; speedup vs baseline: 1.0510x; 1.0510x over previous
//
#include <hip/hip_runtime.h>

// CRF-RNN (C=2) on 56x56, 10 iterations in ONE kernel, plain launch.
// 392 blocks x 256 thr (4 waves) -- the proven round-9 structure.
//
// Math: s = sigmoid(q1-q0); d = (2u-1) - alpha - beta*t_sp/n_sp - gamma*t_bl/n_bl.
//  * spatial kernel separable: 56-tap row conv + column fold; n_sp = Sx*Sy.
//  * bilateral: theta_beta=3 -> exp(-dg^2/6) < 3e-19 for |dg|>16 of 255.
//    Pixels counting-sorted by intensity ONCE (deterministic, stable,
//    atomic-free); per j only the +-16-bucket band is visited (~390 pairs).
//  * norms s-independent: iter-0 computes them, reciprocals in registers.
//
// Sync: zero-sentinel flow control (r8/r9). NEW vs r9: DUAL-ORDER PUBLISH --
// each block stores its 8 sigmoid outputs to BOTH a linear buffer (bufL[j])
// and a sorted-position buffer (bufS[rank[j]]). Wave 0 polls/restages the
// linear field into s_sh; wave 1 concurrently polls/restages the sorted field
// into s_srt. This deletes the per-sync 3136-element LDS permutation scatter
// (7.5M bank-conflict cycles in r9 rocprof) and one barrier per sync.

namespace {

constexpr int NPIX = 3136;
constexpr int WIMG = 56;
constexpr int JPB  = 8;               // j-pixels per block
constexpr int NBLK = NPIX / JPB;      // 392 blocks
constexpr int NTHR = 256;             // 4 waves
constexpr int NBUF = 9;               // syncs after iters 0..8
constexpr int BAND = 16;              // intensity band (buckets)

constexpr float LOG2E = 1.4426950408889634f;
constexpr float C1 = -LOG2E / 18.0f;      // spatial exponent coeff
constexpr float C2 = -LOG2E / 51200.0f;   // bilateral spatial coeff
constexpr float C3 = -LOG2E / 6.0f;       // bilateral intensity coeff

// LDS pool layout (bytes, 16-aligned)
constexpr int O_SSH  = 0;         // float[3136]  s, linear image order
constexpr int O_SSRT = 12544;     // float[3136]  s, intensity-sorted (init: g tmp)
constexpr int O_XYV  = 25088;     // float[3136]  x+64y, sorted (init: H lo)
constexpr int O_GSRT = 37632;     // float[3136]  g, sorted      (init: H hi)
constexpr int O_RANK = 50176;     // u16[3136]    orig -> sorted pos
constexpr int O_OFF  = 56448;     // u32[257]     bucket offsets
constexpr int O_W1C  = 57488;     // float[4][128] shifted spatial tables
constexpr int O_WSY  = 59536;     // float[56]    column weights
constexpr int O_ROWC = 59776;     // float[56*9]  row-conv (padded stride 9)
constexpr int O_SOUT = 61792;     // float[8]
constexpr int POOLSZ = 61824;

#define REDUCE32(v) \
    { v += __shfl_xor(v, 1); v += __shfl_xor(v, 2); v += __shfl_xor(v, 4); \
      v += __shfl_xor(v, 8); v += __shfl_xor(v, 16); }

__global__ __launch_bounds__(NTHR) void crf_all(
    const float* __restrict__ inp,
    const float* __restrict__ spw, const float* __restrict__ blw,
    const float* __restrict__ cmw,
    float* sbufs, float* __restrict__ out)
{
    __shared__ __align__(16) unsigned char pool[POOLSZ];
    float*  s_sh    = (float*)(pool + O_SSH);
    float4* s_sh4   = (float4*)(pool + O_SSH);
    float*  s_srt   = (float*)(pool + O_SSRT);
    float*  xyv_srt = (float*)(pool + O_XYV);
    float*  g_srt   = (float*)(pool + O_GSRT);
    unsigned short* rank = (unsigned short*)(pool + O_RANK);
    unsigned*       offs = (unsigned*)(pool + O_OFF);
    float*  W1c   = (float*)(pool + O_W1C);
    float*  wsy   = (float*)(pool + O_WSY);
    float*  rowc  = (float*)(pool + O_ROWC);
    float*  s_out = (float*)(pool + O_SOUT);
    unsigned short* H  = (unsigned short*)(pool + O_XYV);  // init union (25088B)
    unsigned*       Hz = (unsigned*)(pool + O_XYV);
    float*  tmpg = s_srt;                                   // init alias

    const int t   = threadIdx.x;
    const int bid = blockIdx.x;
    const int sub = t & 31;
    const int jl  = t >> 5;
    const int j   = bid * JPB + jl;
    const int xj0 = (bid * JPB) % WIMG;
    const int yj  = (bid * JPB) / WIMG;
    const int XJ  = xj0 + jl;
    const float xjf = (float)XJ, yjf = (float)yj;

    const float uj = inp[j];
    const float gj = inp[NPIX + j] * 255.0f;

    // collapse the 2x2 weight matrices to 3 scalars
    const float e0 = cmw[2] - cmw[0];
    const float e1 = cmw[3] - cmw[1];
    const float alpha = e0 * (spw[0] + blw[0]) + e1 * (spw[2] + blw[2]);
    const float beta  = e0 * (spw[1] - spw[0]) + e1 * (spw[3] - spw[2]);
    const float gamma = e0 * (blw[1] - blw[0]) + e1 * (blw[3] - blw[2]);

    // ---- I0: stage u and g; build W1 tables; zero H
    {
        const float4* u4 = (const float4*)inp;
        const float4* g4 = (const float4*)(inp + NPIX);
        float4* tg4 = (float4*)tmpg;
        for (int m = t; m < NPIX / 4; m += NTHR) {
            s_sh4[m] = u4[m];
            float4 g = g4[m];
            g.x *= 255.f; g.y *= 255.f; g.z *= 255.f; g.w *= 255.f;
            tg4[m] = g;
        }
        for (int i = t; i < 512; i += NTHR) {       // W1c[r][i]=exp2(C1(56+r-i)^2)
            int r = i >> 7, ii = i & 127;
            float dd = (float)(56 + r - ii);
            W1c[i] = __builtin_amdgcn_exp2f(C1 * dd * dd);
        }
        if (t < 56) {
            float dd = (float)(yj - t);
            wsy[t] = __builtin_amdgcn_exp2f(C1 * dd * dd);
        }
        for (int i = t; i < 6272; i += NTHR) Hz[i] = 0u;
    }
    __syncthreads();
    // ---- I1: per-chunk histogram (49 chunks x 64 px, single-owner rows)
    if (t < 49) {
        unsigned short* Hr = H + t * 256;
        const int mb = t * 64;
        for (int i = 0; i < 64; ++i) {
            int b = (int)tmpg[mb + i]; b = b > 255 ? 255 : b;
            Hr[b] = (unsigned short)(Hr[b] + 1);
        }
    }
    __syncthreads();
    // ---- I2: column prefix per bucket; totals -> offs[b]
    {
        unsigned run = 0;
        for (int c = 0; c < 49; ++c) {
            unsigned short v = H[c * 256 + t];
            H[c * 256 + t] = (unsigned short)run;
            run += v;
        }
        offs[t] = run;
    }
    __syncthreads();
    // ---- I3: exclusive scan offs[0..255] (one wave, 4 buckets/lane)
    if (t < 64) {
        unsigned v0 = offs[4 * t], v1 = offs[4 * t + 1];
        unsigned v2 = offs[4 * t + 2], v3 = offs[4 * t + 3];
        unsigned sum = v0 + v1 + v2 + v3;
        unsigned sc = sum;
        for (int d = 1; d < 64; d <<= 1) {
            unsigned n = __shfl_up(sc, d);
            if (t >= d) sc += n;
        }
        unsigned base = sc - sum;
        offs[4 * t] = base;
        offs[4 * t + 1] = base + v0;
        offs[4 * t + 2] = base + v0 + v1;
        offs[4 * t + 3] = base + v0 + v1 + v2;
        if (t == 63) offs[256] = sc;               // = 3136
    }
    __syncthreads();
    // ---- I4: stable deterministic ranks
    if (t < 49) {
        unsigned short* Hr = H + t * 256;
        const int mb = t * 64;
        for (int i = 0; i < 64; ++i) {
            int b = (int)tmpg[mb + i]; b = b > 255 ? 255 : b;
            rank[mb + i] = (unsigned short)(offs[b] + Hr[b]);
            Hr[b] = (unsigned short)(Hr[b] + 1);
        }
    }
    __syncthreads();
    // ---- I5: fill sorted pos/intensity (overwrites H region)
    for (int m = t; m < NPIX; m += NTHR) {
        int r = rank[m];
        int y = m / WIMG;
        int x = m - y * WIMG;
        xyv_srt[r] = (float)(x + 64 * y);          // exact in fp32
        g_srt[r] = tmpg[m];
    }
    __syncthreads();
    // ---- I6: s_srt for iteration 0 (one-time scatter; tmpg region now dead)
    for (int m = t; m < NPIX; m += NTHR) s_srt[rank[m]] = s_sh[m];
    __syncthreads();

    // n_sp = Sx*Sy (exact separable)
    float sx, sy;
    {
        float dd = xjf - (float)sub;
        sx = __builtin_amdgcn_exp2f(C1 * dd * dd);
        if (sub + 32 < 56) {
            float d2 = xjf - (float)(sub + 32);
            sx += __builtin_amdgcn_exp2f(C1 * d2 * d2);
        }
        REDUCE32(sx);
        dd = yjf - (float)sub;
        sy = __builtin_amdgcn_exp2f(C1 * dd * dd);
        if (sub + 32 < 56) {
            float d2 = yjf - (float)(sub + 32);
            sy += __builtin_amdgcn_exp2f(C1 * d2 * d2);
        }
        REDUCE32(sy);
    }
    const float rnsp = 1.0f / (sx * sy);

    int bj = (int)gj; bj = bj > 255 ? 255 : bj;
    const int blo = (int)offs[bj < BAND ? 0 : bj - BAND];
    const int bhi = (int)offs[(bj + BAND > 255 ? 255 : bj + BAND) + 1];

    // separable spatial: row conv (448 outputs over 256 thr) + column fold
    auto spatial = [&]() -> float {
        const int yA = t >> 3, jl2 = t & 7;
        const int XJ2 = xj0 + jl2;
        const int r = XJ2 & 3;
        const float4* R = (const float4*)(W1c + r * 128 + (56 + r - XJ2));
        {
            const float4* S = s_sh4 + yA * 14;
            float acc = 0.f;
#pragma unroll
            for (int q = 0; q < 14; ++q) {
                float4 w = R[q], sv = S[q];
                acc = fmaf(w.x, sv.x, acc); acc = fmaf(w.y, sv.y, acc);
                acc = fmaf(w.z, sv.z, acc); acc = fmaf(w.w, sv.w, acc);
            }
            rowc[yA * 9 + jl2] = acc;
        }
        const int yB = yA + 32;
        if (yB < 56) {
            const float4* S = s_sh4 + yB * 14;
            float acc = 0.f;
#pragma unroll
            for (int q = 0; q < 14; ++q) {
                float4 w = R[q], sv = S[q];
                acc = fmaf(w.x, sv.x, acc); acc = fmaf(w.y, sv.y, acc);
                acc = fmaf(w.z, sv.z, acc); acc = fmaf(w.w, sv.w, acc);
            }
            rowc[yB * 9 + jl2] = acc;
        }
        __syncthreads();
        float part = wsy[sub] * rowc[sub * 9 + jl];
        if (sub + 32 < 56)
            part = fmaf(wsy[sub + 32], rowc[(sub + 32) * 9 + jl], part);
        REDUCE32(part);
        return part;
    };

    // zero-sentinel poll of a 3136-float field, restage into LDS (lane l of
    // one wave handles quads {q*64+l : q<12} plus l<16: 768+l)
    auto poll_restage = [&](const float* bufp, float4* dst4, int l) {
        const float4* src = (const float4*)bufp;
        float4 vv[12]; float4 vt;
        for (;;) {
#pragma unroll
            for (int q = 0; q < 12; ++q)
                asm volatile("global_load_dwordx4 %0, %1, off sc0 sc1"
                             : "=&v"(vv[q]) : "v"(src + q * 64 + l));
            if (l < 16)
                asm volatile("global_load_dwordx4 %0, %1, off sc0 sc1"
                             : "=&v"(vt) : "v"(src + 768 + l));
            asm volatile("s_waitcnt vmcnt(0)" ::: "memory");
            float mn = 1.0f;                            // s values are >0
#pragma unroll
            for (int q = 0; q < 12; ++q)
                mn = fminf(mn, fminf(fminf(vv[q].x, vv[q].y),
                                     fminf(vv[q].z, vv[q].w)));
            if (l < 16)
                mn = fminf(mn, fminf(fminf(vt.x, vt.y), fminf(vt.z, vt.w)));
            if (!__any(mn == 0.0f)) break;
            __builtin_amdgcn_s_sleep(1);
        }
#pragma unroll
        for (int q = 0; q < 12; ++q) dst4[q * 64 + l] = vv[q];
        if (l < 16) dst4[768 + l] = vt;
    };

    // dual-order publish + parallel two-wave poll/restage (no scatter)
    auto publish_sync = [&](float s, float* bufL, float* bufS) {
        if (sub == 0) s_out[jl] = s;
        __syncthreads();                                // pair pass done too
        if (t < 64) {                                   // wave 0: linear field
            if (t < JPB) {
                const int rj = (int)rank[bid * JPB + t];
                __hip_atomic_store(&bufL[bid * JPB + t], s_out[t],
                                   __ATOMIC_RELAXED, __HIP_MEMORY_SCOPE_AGENT);
                __hip_atomic_store(&bufS[rj], s_out[t],
                                   __ATOMIC_RELAXED, __HIP_MEMORY_SCOPE_AGENT);
            }
            poll_restage(bufL, s_sh4, t);
        } else if (t < 128) {                           // wave 1: sorted field
            poll_restage(bufS, (float4*)s_srt, t - 64);
        }
        __syncthreads();
    };

    const float base = 2.0f * uj - 1.0f - alpha;
    float rnbl, s;

    // ---- iteration 0 (s = u), also accumulates n_bl over the band
    {
        float tsp = spatial();
        float acc = 0.f, nacc = 0.f;
        for (int p = blo + sub; p < bhi; p += 32) {
            float xyv = xyv_srt[p], gv = g_srt[p], sv = s_srt[p];
            float yi = floorf(xyv * 0.015625f);
            float xi = fmaf(-64.f, yi, xyv);
            float ux = xi - xjf, vy = yi - yjf;
            float r2 = fmaf(ux, ux, vy * vy);
            float dg = gv - gj;
            float w = __builtin_amdgcn_exp2f(fmaf(dg * C3, dg, r2 * C2));
            acc = fmaf(w, sv, acc);
            nacc += w;
        }
        REDUCE32(acc); REDUCE32(nacc);
        rnbl = 1.0f / nacc;
        float d = base - beta * (tsp * rnsp) - gamma * (acc * rnbl);
        s = 1.0f / (1.0f + __builtin_amdgcn_exp2f(-d * LOG2E));
    }
    publish_sync(s, sbufs, sbufs + NPIX);

    // ---- iterations 1..9
    for (int k = 1; k < 10; ++k) {
        float tsp = spatial();
        float acc = 0.f;
        for (int p = blo + sub; p < bhi; p += 32) {
            float xyv = xyv_srt[p], gv = g_srt[p], sv = s_srt[p];
            float yi = floorf(xyv * 0.015625f);
            float xi = fmaf(-64.f, yi, xyv);
            float ux = xi - xjf, vy = yi - yjf;
            float r2 = fmaf(ux, ux, vy * vy);
            float dg = gv - gj;
            float w = __builtin_amdgcn_exp2f(fmaf(dg * C3, dg, r2 * C2));
            acc = fmaf(w, sv, acc);
        }
        REDUCE32(acc);
        float d = base - beta * (tsp * rnsp) - gamma * (acc * rnbl);
        s = 1.0f / (1.0f + __builtin_amdgcn_exp2f(-d * LOG2E));
        if (k < 9)
            publish_sync(s, sbufs + k * 2 * NPIX, sbufs + k * 2 * NPIX + NPIX);
        else if (sub == 0) out[j] = s;   // softmax(q)[1] = sigmoid(d)
    }
}

}  // namespace

extern "C" void kernel_launch(void* const* d_in, const int* in_sizes, int n_in,
                              void* d_out, int out_size, void* d_ws, size_t ws_size,
                              hipStream_t stream) {
    const float* inp = (const float*)d_in[0];
    const float* spw = (const float*)d_in[1];
    const float* blw = (const float*)d_in[2];
    const float* cmw = (const float*)d_in[3];
    float* sbufs = (float*)d_ws;    // 9 x (linear + sorted) x 3136 floats
    float* out = (float*)d_out;

    hipMemsetAsync(sbufs, 0, NBUF * 2 * NPIX * sizeof(float), stream);
    crf_all<<<dim3(NBLK), dim3(NTHR), 0, stream>>>(inp, spw, blw, cmw,
                                                   sbufs, out);
}

// Round 12
// 75.880 us; speedup vs baseline: 1.2607x; 1.1996x over previous
//
#include <hip/hip_runtime.h>

// CRF-RNN (C=2) on 56x56, 10 iterations in ONE kernel, plain launch.
// 392 blocks x 256 thr (4 waves), ~36KB LDS -> 2 blocks/CU co-resident.
//
// Math: s = sigmoid(q1-q0); d = (2u-1) - alpha - beta*t_sp/n_sp - gamma*t_bl/n_bl.
//  * spatial kernel separable: 56-tap row conv (ALIGNED per-j weight rows,
//    stride 224B -- the r9/r11 shifted-table unaligned b128 reads were the
//    ~7M LDS bank-conflict cycles) + column fold; n_sp = Sx*Sy exactly.
//  * bilateral: theta_beta=3 -> weight < 5e-17 outside +-16 intensity buckets.
//    Pixels counting-sorted by intensity ONCE; band loop walks the sorted
//    index m_srt[p] (u16) and reads s_sh[m] directly -- NO per-sync sorted-s
//    scatter, no xyv array (x,y recovered via magic-mul m/56).
//  * norms s-independent: iter-0 computes them, reciprocals in registers.
//
// Sync: zero-sentinel flow control (proven r8/r9): sigmoid outputs are never
// 0.0f; 9 distinct pre-zeroed publish buffers; publish = 8 relaxed agent
// stores (LLC-coherent); consume = ALL 256 threads poll 3-4 quads each with
// global_load_dwordx4 sc0 sc1, per-thread done flags, block-wide vote via
// LDS wave flags; restage = each thread writes its own quads (contiguous).

namespace {

constexpr int NPIX = 3136;
constexpr int WIMG = 56;
constexpr int JPB  = 8;               // j-pixels per block
constexpr int NBLK = NPIX / JPB;      // 392 blocks
constexpr int NTHR = 256;             // 4 waves
constexpr int NQ   = NPIX / 4;        // 784 quads
constexpr int NBUF = 9;               // publish buffers (syncs after iters 0..8)
constexpr int BAND = 16;              // intensity band (buckets)

constexpr float LOG2E = 1.4426950408889634f;
constexpr float C1 = -LOG2E / 18.0f;      // spatial exponent coeff
constexpr float C2 = -LOG2E / 51200.0f;   // bilateral spatial coeff
constexpr float C3 = -LOG2E / 6.0f;       // bilateral intensity coeff

// LDS pool layout (bytes, 16-aligned)
constexpr int O_SSH  = 0;         // float[3136] s, linear image order
constexpr int O_GSRT = 12544;     // float[3136] g, sorted order
                                  // (init: H hist u16[49][256]=25088B overlays SSH+GSRT)
constexpr int O_MSRT = 25088;     // u16[3136]  sorted pos -> linear pixel idx
constexpr int O_OFF  = 31360;     // u32[257]   bucket offsets (pad 1040)
constexpr int O_WSX  = 32400;     // float[8][56]  per-j row weights (aligned rows)
constexpr int O_WSY  = 34192;     // float[56]     column weights (yj same for all j)
constexpr int O_ROWC = 34416;     // float[56*9]   row-conv out (pad stride 9)
constexpr int O_SOUT = 36432;     // float[8]
constexpr int O_WFLG = 36464;     // int[4]
constexpr int POOLSZ = 36480;

#define REDUCE32(v) \
    { v += __shfl_xor(v, 1); v += __shfl_xor(v, 2); v += __shfl_xor(v, 4); \
      v += __shfl_xor(v, 8); v += __shfl_xor(v, 16); }

__global__ __launch_bounds__(NTHR) void crf_all(
    const float* __restrict__ inp,
    const float* __restrict__ spw, const float* __restrict__ blw,
    const float* __restrict__ cmw,
    float* sbufs, float* __restrict__ out)
{
    __shared__ __align__(16) unsigned char pool[POOLSZ];
    float*  s_sh  = (float*)(pool + O_SSH);
    float4* s_sh4 = (float4*)(pool + O_SSH);
    float*  g_srt = (float*)(pool + O_GSRT);
    unsigned short* m_srt = (unsigned short*)(pool + O_MSRT);
    unsigned*       offs  = (unsigned*)(pool + O_OFF);
    float*  wsx   = (float*)(pool + O_WSX);
    float*  wsy   = (float*)(pool + O_WSY);
    float*  rowc  = (float*)(pool + O_ROWC);
    float*  s_out = (float*)(pool + O_SOUT);
    int*    wflag = (int*)(pool + O_WFLG);
    unsigned short* H  = (unsigned short*)(pool + O_SSH);   // init union (25088B)
    unsigned*       Hz = (unsigned*)(pool + O_SSH);

    const int t   = threadIdx.x;
    const int bid = blockIdx.x;
    const int sub = t & 31;
    const int jl  = t >> 5;
    const int j   = bid * JPB + jl;
    const int xj0 = (bid * JPB) % WIMG;   // JPB=8 divides 56: all j share a row
    const int yj  = (bid * JPB) / WIMG;
    const float xjf = (float)(xj0 + jl), yjf = (float)yj;

    const float uj = inp[j];
    const float gj = inp[NPIX + j] * 255.0f;

    // collapse the 2x2 weight matrices to 3 scalars
    const float e0 = cmw[2] - cmw[0];
    const float e1 = cmw[3] - cmw[1];
    const float alpha = e0 * (spw[0] + blw[0]) + e1 * (spw[2] + blw[2]);
    const float beta  = e0 * (spw[1] - spw[0]) + e1 * (spw[3] - spw[2]);
    const float gamma = e0 * (blw[1] - blw[0]) + e1 * (blw[3] - blw[2]);

    // ---- I0: zero H; build aligned weight tables (don't overlap H)
    for (int i = t; i < 6272; i += NTHR) Hz[i] = 0u;
    for (int idx = t; idx < JPB * 56; idx += NTHR) {
        const int jlw = idx / 56, x = idx - jlw * 56;
        const float dd = (float)(xj0 + jlw - x);
        wsx[idx] = __builtin_amdgcn_exp2f(C1 * dd * dd);
    }
    if (t < 56) {
        const float dd = (float)(yj - t);
        wsy[t] = __builtin_amdgcn_exp2f(C1 * dd * dd);
    }
    __syncthreads();
    // ---- I1: per-chunk histogram (49 chunks x 64 px, single-owner rows)
    if (t < 49) {
        unsigned short* Hr = H + t * 256;
        const int mb = t * 64;
        for (int i = 0; i < 64; ++i) {
            int b = (int)(inp[NPIX + mb + i] * 255.0f);
            b = b > 255 ? 255 : b;
            Hr[b] = (unsigned short)(Hr[b] + 1);
        }
    }
    __syncthreads();
    // ---- I2: column prefix per bucket; totals -> offs[b]
    {
        unsigned run = 0;
        for (int c = 0; c < 49; ++c) {
            unsigned short v = H[c * 256 + t];
            H[c * 256 + t] = (unsigned short)run;
            run += v;
        }
        offs[t] = run;
    }
    __syncthreads();
    // ---- I3: exclusive scan offs[0..255] (one wave, 4 buckets/lane)
    if (t < 64) {
        unsigned v0 = offs[4 * t], v1 = offs[4 * t + 1];
        unsigned v2 = offs[4 * t + 2], v3 = offs[4 * t + 3];
        unsigned sum = v0 + v1 + v2 + v3;
        unsigned sc = sum;
        for (int d = 1; d < 64; d <<= 1) {
            unsigned n = __shfl_up(sc, d);
            if (t >= d) sc += n;
        }
        unsigned base = sc - sum;
        offs[4 * t] = base;
        offs[4 * t + 1] = base + v0;
        offs[4 * t + 2] = base + v0 + v1;
        offs[4 * t + 3] = base + v0 + v1 + v2;
        if (t == 63) offs[256] = sc;               // = 3136
    }
    __syncthreads();
    // ---- I4: stable deterministic ranks -> m_srt (separate region, no clash)
    if (t < 49) {
        unsigned short* Hr = H + t * 256;
        const int mb = t * 64;
        for (int i = 0; i < 64; ++i) {
            int b = (int)(inp[NPIX + mb + i] * 255.0f);
            b = b > 255 ? 255 : b;
            int r = (int)offs[b] + (int)Hr[b];
            Hr[b] = (unsigned short)(Hr[b] + 1);
            m_srt[r] = (unsigned short)(mb + i);
        }
    }
    __syncthreads();
    // ---- I5: H dead. Fill g_srt (sorted) and s_sh = u (linear).
    for (int p = t; p < NPIX; p += NTHR)
        g_srt[p] = inp[NPIX + (int)m_srt[p]] * 255.0f;
    {
        const float4* u4 = (const float4*)inp;
        for (int q = t; q < NQ; q += NTHR) s_sh4[q] = u4[q];
    }
    __syncthreads();

    // n_sp = Sx*Sy (exact separable)
    float sx, sy;
    {
        float dd = xjf - (float)sub;
        sx = __builtin_amdgcn_exp2f(C1 * dd * dd);
        if (sub + 32 < 56) {
            float d2 = xjf - (float)(sub + 32);
            sx += __builtin_amdgcn_exp2f(C1 * d2 * d2);
        }
        REDUCE32(sx);
        dd = yjf - (float)sub;
        sy = __builtin_amdgcn_exp2f(C1 * dd * dd);
        if (sub + 32 < 56) {
            float d2 = yjf - (float)(sub + 32);
            sy += __builtin_amdgcn_exp2f(C1 * d2 * d2);
        }
        REDUCE32(sy);
    }
    const float rnsp = 1.0f / (sx * sy);

    int bj = (int)gj; bj = bj > 255 ? 255 : bj;
    const int blo = (int)offs[bj < BAND ? 0 : bj - BAND];
    const int bhi = (int)offs[(bj + BAND > 255 ? 255 : bj + BAND) + 1];

    // separable spatial: row conv (448 outputs over 256 thr) + column fold.
    // Weight rows are ALIGNED (stride 56 floats = 14 float4) -> clean b128.
    auto spatial = [&]() -> float {
        const int yA = t >> 3, jl2 = t & 7;
        const float4* R = (const float4*)(wsx + jl2 * 56);
        {
            const float4* S = s_sh4 + yA * 14;
            float acc = 0.f;
#pragma unroll
            for (int q = 0; q < 14; ++q) {
                float4 w = R[q], sv = S[q];
                acc = fmaf(w.x, sv.x, acc); acc = fmaf(w.y, sv.y, acc);
                acc = fmaf(w.z, sv.z, acc); acc = fmaf(w.w, sv.w, acc);
            }
            rowc[yA * 9 + jl2] = acc;
        }
        const int yB = yA + 32;
        if (yB < 56) {
            const float4* S = s_sh4 + yB * 14;
            float acc = 0.f;
#pragma unroll
            for (int q = 0; q < 14; ++q) {
                float4 w = R[q], sv = S[q];
                acc = fmaf(w.x, sv.x, acc); acc = fmaf(w.y, sv.y, acc);
                acc = fmaf(w.z, sv.z, acc); acc = fmaf(w.w, sv.w, acc);
            }
            rowc[yB * 9 + jl2] = acc;
        }
        __syncthreads();
        float part = wsy[sub] * rowc[sub * 9 + jl];
        if (sub + 32 < 56)
            part = fmaf(wsy[sub + 32], rowc[(sub + 32) * 9 + jl], part);
        REDUCE32(part);
        return part;
    };

    // bilateral band pass over sorted positions [blo,bhi), stride 32
    auto bilateral = [&](float* nacc_out) -> float {
        float acc = 0.f, nacc = 0.f;
        for (int p = blo + sub; p < bhi; p += 32) {
            const int m = (int)m_srt[p];
            const float gv = g_srt[p];
            const float sv = s_sh[m];
            const int yi = (m * 9363) >> 19;       // m/56 (exact for m<3136)
            const int xi = m - yi * 56;
            const float ux = (float)xi - xjf, vy = (float)yi - yjf;
            const float r2 = fmaf(ux, ux, vy * vy);
            const float dg = gv - gj;
            const float w = __builtin_amdgcn_exp2f(fmaf(dg * C3, dg, r2 * C2));
            acc = fmaf(w, sv, acc);
            if (nacc_out) nacc += w;
        }
        REDUCE32(acc);
        if (nacc_out) { REDUCE32(nacc); *nacc_out = nacc; }
        return acc;
    };

    // publish + zero-sentinel sync: all 256 threads poll 3-4 quads each
    auto publish_sync = [&](float s, float* buf) {
        if (sub == 0) s_out[jl] = s;
        __syncthreads();                            // all compute done
        if (t < JPB)
            __hip_atomic_store(&buf[bid * JPB + t], s_out[t],
                               __ATOMIC_RELAXED, __HIP_MEMORY_SCOPE_AGENT);
        const float4* src = (const float4*)buf;
        float4 a, b, c, d;
        bool done = false;
        const bool four = (t < 16);
        for (;;) {
            if (!done) {
                asm volatile("global_load_dwordx4 %0, %1, off sc0 sc1"
                             : "=&v"(a) : "v"(src + t));
                asm volatile("global_load_dwordx4 %0, %1, off sc0 sc1"
                             : "=&v"(b) : "v"(src + 256 + t));
                asm volatile("global_load_dwordx4 %0, %1, off sc0 sc1"
                             : "=&v"(c) : "v"(src + 512 + t));
                if (four)
                    asm volatile("global_load_dwordx4 %0, %1, off sc0 sc1"
                                 : "=&v"(d) : "v"(src + 768 + t));
                asm volatile("s_waitcnt vmcnt(0)" ::: "memory");
                float mn = fminf(fminf(fminf(a.x, a.y), fminf(a.z, a.w)),
                                 fminf(fminf(b.x, b.y),
                                       fminf(fminf(b.z, b.w),
                                             fminf(fminf(c.x, c.y),
                                                   fminf(c.z, c.w)))));
                if (four)
                    mn = fminf(mn, fminf(fminf(d.x, d.y), fminf(d.z, d.w)));
                done = (mn != 0.0f);                // s values are > 0
            }
            const bool wall = (__all(done) != 0);
            if ((t & 63) == 0) wflag[t >> 6] = wall ? 1 : 0;
            __syncthreads();
            if (wflag[0] && wflag[1] && wflag[2] && wflag[3]) break;
            __syncthreads();
            __builtin_amdgcn_s_sleep(1);
        }
        s_sh4[t] = a;
        s_sh4[256 + t] = b;
        s_sh4[512 + t] = c;
        if (four) s_sh4[768 + t] = d;
        __syncthreads();
    };

    const float base = 2.0f * uj - 1.0f - alpha;
    float rnbl, s;

    // ---- iteration 0 (s = u), also accumulates n_bl over the band
    {
        float tsp = spatial();
        float nacc;
        float acc = bilateral(&nacc);
        rnbl = 1.0f / nacc;
        float d = base - beta * (tsp * rnsp) - gamma * (acc * rnbl);
        s = 1.0f / (1.0f + __builtin_amdgcn_exp2f(-d * LOG2E));
    }
    publish_sync(s, sbufs);

    // ---- iterations 1..9
    for (int k = 1; k < 10; ++k) {
        float tsp = spatial();
        float acc = bilateral(nullptr);
        float d = base - beta * (tsp * rnsp) - gamma * (acc * rnbl);
        s = 1.0f / (1.0f + __builtin_amdgcn_exp2f(-d * LOG2E));
        if (k < 9) publish_sync(s, sbufs + k * NPIX);
        else if (sub == 0) out[j] = s;   // softmax(q)[1] = sigmoid(d)
    }
}

}  // namespace

extern "C" void kernel_launch(void* const* d_in, const int* in_sizes, int n_in,
                              void* d_out, int out_size, void* d_ws, size_t ws_size,
                              hipStream_t stream) {
    const float* inp = (const float*)d_in[0];
    const float* spw = (const float*)d_in[1];
    const float* blw = (const float*)d_in[2];
    const float* cmw = (const float*)d_in[3];
    float* sbufs = (float*)d_ws;          // 9 x 3136 floats, zero = "not yet"
    float* out = (float*)d_out;

    hipMemsetAsync(sbufs, 0, NBUF * NPIX * sizeof(float), stream);
    crf_all<<<dim3(NBLK), dim3(NTHR), 0, stream>>>(inp, spw, blw, cmw,
                                                   sbufs, out);
}